// Round 4
// baseline (198.604 us; speedup 1.0000x reference)
//
#include <hip/hip_runtime.h>

#define TT 2048
#define DD 1024
#define HH 16
#define DH 64
#define QKV_N 3072

typedef __attribute__((ext_vector_type(8))) short bf16x8;
typedef __attribute__((ext_vector_type(4))) float f32x4;

__device__ inline short f2bf(float f) {
    union { float f; unsigned u; } v; v.f = f;
    unsigned r = v.u + 0x7fff + ((v.u >> 16) & 1);  // RNE
    return (short)(r >> 16);
}

__device__ inline f32x4 mfma16(bf16x8 a, bf16x8 b, f32x4 c) {
    return __builtin_amdgcn_mfma_f32_16x16x32_bf16(a, b, c, 0, 0, 0);
}

// async global->LDS, 16B per lane; LDS dest must be wave-uniform base (+lane*16)
__device__ __forceinline__ void gload16(const void* g, void* l) {
    __builtin_amdgcn_global_load_lds(
        (const __attribute__((address_space(1))) unsigned int*)g,
        (__attribute__((address_space(3))) unsigned int*)l, 16, 0, 0);
}

// ---------------------------------------------------------------------------
// 1. scan: seg = cumsum(done), total, aux[0..31]=start_tile per t-tile,
//    aux[32]=first chunk containing a last-segment token
// ---------------------------------------------------------------------------
__global__ __launch_bounds__(256) void scan_kernel(const int* __restrict__ done,
                                                   int* __restrict__ seg,
                                                   int* __restrict__ totalp,
                                                   int* __restrict__ aux) {
    __shared__ int part[256];
    __shared__ int excl[256];
    __shared__ int segl[2048];
    __shared__ int tot;
    int tid = threadIdx.x;
    int base = tid * 8;
    int local[8];
    int run = 0;
#pragma unroll
    for (int i = 0; i < 8; ++i) { run += (done[base + i] != 0) ? 1 : 0; local[i] = run; }
    part[tid] = run;
    __syncthreads();
    if (tid < 64) {
        int p4[4];
#pragma unroll
        for (int i = 0; i < 4; ++i) p4[i] = part[tid * 4 + i];
        int s = p4[0] + p4[1] + p4[2] + p4[3];
        int v = s;
#pragma unroll
        for (int off = 1; off < 64; off <<= 1) {
            int u = __shfl_up(v, off);
            if (tid >= off) v += u;
        }
        int ex = v - s;
#pragma unroll
        for (int i = 0; i < 4; ++i) { excl[tid * 4 + i] = ex; ex += p4[i]; }
        if (tid == 63) { totalp[0] = v; tot = v; }
    }
    __syncthreads();
    int off = excl[tid];
#pragma unroll
    for (int i = 0; i < 8; ++i) {
        int sv = off + local[i];
        seg[base + i] = sv;
        segl[base + i] = sv;
    }
    __syncthreads();
    if (tid < 33) {
        int target = (tid < 32) ? segl[tid * 64] : tot;
        int lo = 0, hi = 2047;  // first index with segl >= target (target always present)
        while (lo < hi) { int mid = (lo + hi) >> 1; if (segl[mid] >= target) hi = mid; else lo = mid + 1; }
        aux[tid] = lo >> 6;
    }
}

// ---------------------------------------------------------------------------
// 2. prep: fused cast + transposes
//    blocks [0,1024): x fp32 -> bf16
//    blocks [1024,1792): w_qkv^T -> wqT
//    blocks [1792,2048): w_out^T -> woT
//    blocks [2048,2064): state^T -> stT
// ---------------------------------------------------------------------------
__device__ void transpose_tile(const float* __restrict__ in, short* __restrict__ out,
                               int R, int C, int r0, int c0, float (*tile)[65]) {
    int tid = threadIdx.x;
#pragma unroll
    for (int p = 0; p < 4; ++p) {
        int ch = tid + p * 256;
        int r = ch >> 4, c4 = (ch & 15) * 4;
        float4 v = *(const float4*)&in[(size_t)(r0 + r) * C + c0 + c4];
        tile[r][c4] = v.x; tile[r][c4 + 1] = v.y; tile[r][c4 + 2] = v.z; tile[r][c4 + 3] = v.w;
    }
    __syncthreads();
#pragma unroll
    for (int p = 0; p < 2; ++p) {
        int ch = tid + p * 256;
        int c = ch >> 3, r8 = (ch & 7) * 8;
        short tmp[8];
#pragma unroll
        for (int i = 0; i < 8; ++i) tmp[i] = f2bf(tile[r8 + i][c]);
        *(float4*)&out[(size_t)(c0 + c) * R + r0 + r8] = *(float4*)tmp;
    }
}

__global__ __launch_bounds__(256) void prep_kernel(const float* __restrict__ x,
                                                   const float* __restrict__ w_qkv,
                                                   const float* __restrict__ w_out,
                                                   const float* __restrict__ state,
                                                   short* __restrict__ x_bf,
                                                   short* __restrict__ wqT,
                                                   short* __restrict__ woT,
                                                   short* __restrict__ stT) {
    __shared__ float tile[64][65];
    int b = blockIdx.x;
    if (b < 1024) {
        int i = (b * 256 + threadIdx.x) * 8;
        float4 a = *(const float4*)&x[i];
        float4 c = *(const float4*)&x[i + 4];
        short tmp[8] = {f2bf(a.x), f2bf(a.y), f2bf(a.z), f2bf(a.w),
                        f2bf(c.x), f2bf(c.y), f2bf(c.z), f2bf(c.w)};
        *(float4*)&x_bf[i] = *(float4*)tmp;
    } else if (b < 1792) {
        int bb = b - 1024;  // w_qkv: R=1024 C=3072, grid 16 x 48
        transpose_tile(w_qkv, wqT, DD, QKV_N, (bb & 15) * 64, (bb >> 4) * 64, tile);
    } else if (b < 2048) {
        int bb = b - 1792;  // w_out: 1024x1024, grid 16 x 16
        transpose_tile(w_out, woT, DD, DD, (bb & 15) * 64, (bb >> 4) * 64, tile);
    } else {
        int h = b - 2048;   // state head transpose 64x64
        transpose_tile(state + (size_t)h * 4096, stT + (size_t)h * 4096, DH, DH, 0, 0, tile);
    }
}

// ---------------------------------------------------------------------------
// 3. bf16 MFMA GEMM (m97 pattern): C[M,N] = A[M,K] @ BT[N,K]^T + bias
//    128x128 tile, BK=32, unpadded LDS, global_load_lds width-16 staging.
// ---------------------------------------------------------------------------
template <bool BF16OUT>
__global__ __launch_bounds__(256) void gemm_bt(const short* __restrict__ A,
                                               const short* __restrict__ BT,
                                               const float* __restrict__ bias,
                                               void* __restrict__ Cout,
                                               int M, int N, int K) {
    __shared__ short As[128 * 32];
    __shared__ short Bs[128 * 32];
    int tid = threadIdx.x;
    int wave = tid >> 6, lane = tid & 63;
    int quad = lane >> 4, l15 = lane & 15;
    int m0 = blockIdx.x * 128, n0 = blockIdx.y * 128;
    int wr = (wave >> 1) * 64, wc = (wave & 1) * 64;

    // staging: lane i of wave w covers row w*16 + i/4 (+64 for 2nd inst), k-chunk (i&3)*8
    int srow = wave * 16 + (lane >> 2);
    int scol = (lane & 3) * 8;
    const short* Ag = A + (size_t)(m0 + srow) * K + scol;
    const short* Bg = BT + (size_t)(n0 + srow) * K + scol;
    short* As0 = &As[(wave * 16) * 32];
    short* As1 = &As[(64 + wave * 16) * 32];
    short* Bs0 = &Bs[(wave * 16) * 32];
    short* Bs1 = &Bs[(64 + wave * 16) * 32];

    f32x4 acc[4][4] = {};
    for (int k0 = 0; k0 < K; k0 += 32) {
        __syncthreads();
        gload16(Ag + k0, As0);
        gload16(Ag + (size_t)64 * K + k0, As1);
        gload16(Bg + k0, Bs0);
        gload16(Bg + (size_t)64 * K + k0, Bs1);
        __syncthreads();
        bf16x8 af[4], bfr[4];
#pragma unroll
        for (int i = 0; i < 4; ++i) {
            af[i]  = *(const bf16x8*)&As[(wr + i * 16 + l15) * 32 + quad * 8];
            bfr[i] = *(const bf16x8*)&Bs[(wc + i * 16 + l15) * 32 + quad * 8];
        }
#pragma unroll
        for (int i = 0; i < 4; ++i)
#pragma unroll
            for (int j = 0; j < 4; ++j)
                acc[i][j] = mfma16(af[i], bfr[j], acc[i][j]);
    }
#pragma unroll
    for (int i = 0; i < 4; ++i)
#pragma unroll
        for (int j = 0; j < 4; ++j)
#pragma unroll
            for (int r = 0; r < 4; ++r) {
                int row = m0 + wr + i * 16 + quad * 4 + r;
                int col = n0 + wc + j * 16 + l15;
                float v = acc[i][j][r] + bias[col];
                if (BF16OUT) ((short*)Cout)[(size_t)row * N + col] = f2bf(v);
                else        ((float*)Cout)[(size_t)row * N + col] = v;
            }
}

// ---------------------------------------------------------------------------
// 4. attention. block=(h, t-tile of 64), 4 waves; s-loop starts at aux[tt].
// ---------------------------------------------------------------------------
#define SQ 72

__global__ __launch_bounds__(256) void attn_mfma(const short* __restrict__ qkv,
                                                 const short* __restrict__ stateT,
                                                 const int* __restrict__ seg,
                                                 const int* __restrict__ aux,
                                                 short* __restrict__ outb) {
    __shared__ short Qs[64 * SQ];
    __shared__ short Ks[64 * SQ];
    __shared__ short Vt[64 * SQ];
    __shared__ short Ss[64 * SQ];
    __shared__ int segT[64], segS[64];

    int h = blockIdx.x, tt = blockIdx.y;
    int t0 = tt * 64;
    int tid = threadIdx.x, wave = tid >> 6, lane = tid & 63;
    int quad = lane >> 4, l15 = lane & 15;
    int myt = wave * 16;

    bool need_state = (seg[t0] == 0);  // any row before first reset?
#pragma unroll
    for (int p = 0; p < 2; ++p) {
        int idx = tid + p * 256;
        int r = idx >> 3, c8 = (idx & 7) * 8;
        *(float4*)&Qs[r * SQ + c8] = *(const float4*)&qkv[(size_t)(t0 + r) * QKV_N + h * DH + c8];
        if (need_state)
            *(float4*)&Ks[r * SQ + c8] = *(const float4*)&stateT[(size_t)h * 4096 + r * 64 + c8];
    }
    if (tid < 64) segT[tid] = seg[t0 + tid];
    __syncthreads();

    bf16x8 qf[2];
    qf[0] = *(const bf16x8*)&Qs[(myt + l15) * SQ + quad * 8];
    qf[1] = *(const bf16x8*)&Qs[(myt + l15) * SQ + 32 + quad * 8];

    f32x4 acc[4] = {};
    if (need_state) {
#pragma unroll
        for (int j = 0; j < 4; ++j) {
            bf16x8 b0 = *(const bf16x8*)&Ks[(j * 16 + l15) * SQ + quad * 8];
            bf16x8 b1 = *(const bf16x8*)&Ks[(j * 16 + l15) * SQ + 32 + quad * 8];
            acc[j] = mfma16(qf[0], b0, acc[j]);
            acc[j] = mfma16(qf[1], b1, acc[j]);
        }
#pragma unroll
        for (int r = 0; r < 4; ++r) {
            int t = myt + quad * 4 + r;
            if (segT[t] != 0) { acc[0][r] = 0.f; acc[1][r] = 0.f; acc[2][r] = 0.f; acc[3][r] = 0.f; }
        }
    }

    int st0 = aux[tt];
    for (int st = st0; st <= tt; ++st) {
        int s0 = st * 64;
        __syncthreads();
#pragma unroll
        for (int p = 0; p < 2; ++p) {
            int idx = tid + p * 256;
            int r = idx >> 3, c8 = (idx & 7) * 8;
            *(float4*)&Ks[r * SQ + c8] = *(const float4*)&qkv[(size_t)(s0 + r) * QKV_N + DD + h * DH + c8];
            union { float4 f; short s[8]; } uv;
            uv.f = *(const float4*)&qkv[(size_t)(s0 + r) * QKV_N + 2 * DD + h * DH + c8];
#pragma unroll
            for (int ii = 0; ii < 8; ++ii) {
                int i = (ii + lane) & 7;
                Vt[(c8 + i) * SQ + r] = uv.s[i];
            }
        }
        if (tid < 64) segS[tid] = seg[s0 + tid];
        __syncthreads();

        f32x4 sacc[4] = {};
#pragma unroll
        for (int j = 0; j < 4; ++j) {
            bf16x8 b0 = *(const bf16x8*)&Ks[(j * 16 + l15) * SQ + quad * 8];
            bf16x8 b1 = *(const bf16x8*)&Ks[(j * 16 + l15) * SQ + 32 + quad * 8];
            sacc[j] = mfma16(qf[0], b0, sacc[j]);
            sacc[j] = mfma16(qf[1], b1, sacc[j]);
        }
#pragma unroll
        for (int j = 0; j < 4; ++j)
#pragma unroll
            for (int r = 0; r < 4; ++r) {
                int t = myt + quad * 4 + r;
                int s = j * 16 + l15;
                bool ok = (segS[s] == segT[t]) && (s0 + s <= t0 + t);
                Ss[t * SQ + s] = ok ? f2bf(sacc[j][r]) : (short)0;
            }
        __syncthreads();

        bf16x8 sf0 = *(const bf16x8*)&Ss[(myt + l15) * SQ + quad * 8];
        bf16x8 sf1 = *(const bf16x8*)&Ss[(myt + l15) * SQ + 32 + quad * 8];
#pragma unroll
        for (int j = 0; j < 4; ++j) {
            bf16x8 b0 = *(const bf16x8*)&Vt[(j * 16 + l15) * SQ + quad * 8];
            bf16x8 b1 = *(const bf16x8*)&Vt[(j * 16 + l15) * SQ + 32 + quad * 8];
            acc[j] = mfma16(sf0, b0, acc[j]);
            acc[j] = mfma16(sf1, b1, acc[j]);
        }
    }

#pragma unroll
    for (int j = 0; j < 4; ++j)
#pragma unroll
        for (int r = 0; r < 4; ++r) {
            int t = t0 + myt + quad * 4 + r;
            int e = j * 16 + l15;
            outb[(size_t)t * DD + h * DH + e] = f2bf(acc[j][r]);
        }
}

// ---------------------------------------------------------------------------
// 5a. state partials for active chunks only (ct >= aux[32])
// ---------------------------------------------------------------------------
__global__ __launch_bounds__(256) void state_mfma(const short* __restrict__ qkv,
                                                  const int* __restrict__ seg,
                                                  const int* __restrict__ totalp,
                                                  const int* __restrict__ aux,
                                                  float* __restrict__ part) {
    __shared__ short Kt[64 * SQ];
    __shared__ short Vt[64 * SQ];
    int h = blockIdx.x, ct = blockIdx.y;
    if (ct < aux[32]) return;  // inactive chunk: nothing written, reduce skips it
    int t0 = ct * 64;
    int total = totalp[0];
    float* my = part + ((size_t)ct * HH + h) * 4096;
    int tid = threadIdx.x, wave = tid >> 6, lane = tid & 63;
    int quad = lane >> 4, l15 = lane & 15;

#pragma unroll
    for (int p = 0; p < 2; ++p) {
        int idx = tid + p * 256;
        int r = idx >> 3, c8 = (idx & 7) * 8;
        bool keep = (seg[t0 + r] == total);
        union { float4 f; short s[8]; } uk, uv;
        uk.f = *(const float4*)&qkv[(size_t)(t0 + r) * QKV_N + DD + h * DH + c8];
        uv.f = *(const float4*)&qkv[(size_t)(t0 + r) * QKV_N + 2 * DD + h * DH + c8];
#pragma unroll
        for (int ii = 0; ii < 8; ++ii) {
            int i = (ii + lane) & 7;
            Kt[(c8 + i) * SQ + r] = keep ? uk.s[i] : (short)0;
            Vt[(c8 + i) * SQ + r] = uv.s[i];
        }
    }
    __syncthreads();

    int myd = wave * 16;
    bf16x8 a0 = *(const bf16x8*)&Kt[(myd + l15) * SQ + quad * 8];
    bf16x8 a1 = *(const bf16x8*)&Kt[(myd + l15) * SQ + 32 + quad * 8];
    f32x4 acc[4] = {};
#pragma unroll
    for (int j = 0; j < 4; ++j) {
        bf16x8 b0 = *(const bf16x8*)&Vt[(j * 16 + l15) * SQ + quad * 8];
        bf16x8 b1 = *(const bf16x8*)&Vt[(j * 16 + l15) * SQ + 32 + quad * 8];
        acc[j] = mfma16(a0, b0, acc[j]);
        acc[j] = mfma16(a1, b1, acc[j]);
    }
#pragma unroll
    for (int j = 0; j < 4; ++j)
#pragma unroll
        for (int r = 0; r < 4; ++r)
            my[(myd + quad * 4 + r) * DH + j * 16 + l15] = acc[j][r];
}

// ---------------------------------------------------------------------------
// 5b. reduce active partials
// ---------------------------------------------------------------------------
__global__ __launch_bounds__(256) void state_reduce(const float* __restrict__ part,
                                                    const float* __restrict__ state,
                                                    const int* __restrict__ totalp,
                                                    const int* __restrict__ aux,
                                                    float* __restrict__ out) {
    int f = (blockIdx.x * 256 + threadIdx.x) * 4;
    bool done_any = totalp[0] > 0;
    int fc = aux[32];
    float4 acc = done_any ? make_float4(0.f, 0.f, 0.f, 0.f) : *(const float4*)&state[f];
    for (int ct = fc; ct < 32; ++ct) {
        float4 p = *(const float4*)&part[(size_t)ct * (HH * 4096) + f];
        acc.x += p.x; acc.y += p.y; acc.z += p.z; acc.w += p.w;
    }
    *(float4*)&out[f] = acc;
}

// ---------------------------------------------------------------------------
// Host launcher
// ---------------------------------------------------------------------------
extern "C" void kernel_launch(void* const* d_in, const int* in_sizes, int n_in,
                              void* d_out, int out_size, void* d_ws, size_t ws_size,
                              hipStream_t stream) {
    const float* state = (const float*)d_in[0];
    const float* x     = (const float*)d_in[1];
    const int*   done  = (const int*)d_in[2];
    const float* w_qkv = (const float*)d_in[3];
    const float* b_qkv = (const float*)d_in[4];
    const float* w_out = (const float*)d_in[5];
    const float* b_out = (const float*)d_in[6];

    char* ws = (char*)d_ws;
    int*   seg    = (int*)ws;                                  // 8 KB
    int*   totalp = (int*)(ws + 8192);
    int*   aux    = (int*)(ws + 8256);                         // 33 ints
    short* x_bf   = (short*)(ws + 8448);                       // 4 MB
    short* wqT    = (short*)(ws + 8448 + 4194304);             // 6 MB
    short* woT    = (short*)(ws + 8448 + 10485760);            // 2 MB
    short* stT    = (short*)(ws + 8448 + 12582912);            // 128 KB
    short* qkvb   = (short*)(ws + 8448 + 12713984);            // 12 MB
    short* outb   = (short*)(ws + 8448 + 25296896);            // 4 MB
    float* spart  = (float*)(ws + 8448);                       // aliases x_bf/wqT (dead)

    float* new_state_out = (float*)d_out;
    float* x_out         = (float*)d_out + HH * DH * DH;

    scan_kernel<<<1, 256, 0, stream>>>(done, seg, totalp, aux);
    prep_kernel<<<2064, 256, 0, stream>>>(x, w_qkv, w_out, state, x_bf, wqT, woT, stT);

    gemm_bt<true><<<dim3(TT / 128, QKV_N / 128), 256, 0, stream>>>(
        x_bf, wqT, b_qkv, qkvb, TT, QKV_N, DD);

    attn_mfma<<<dim3(HH, TT / 64), 256, 0, stream>>>(qkvb, stT, seg, aux, outb);

    state_mfma<<<dim3(HH, TT / 64), 256, 0, stream>>>(qkvb, seg, totalp, aux, spart);
    state_reduce<<<64, 256, 0, stream>>>(spart, state, totalp, aux, new_state_out);

    gemm_bt<false><<<dim3(TT / 128, DD / 128), 256, 0, stream>>>(
        outb, woT, b_out, x_out, TT, DD, DD);
}

// Round 5
// 182.953 us; speedup vs baseline: 1.0855x; 1.0855x over previous
//
#include <hip/hip_runtime.h>

#define TT 2048
#define DD 1024
#define HH 16
#define DH 64
#define QKV_N 3072
#define QKW 2048  // qk buffer width (Q cols 0..1023, K cols 1024..2047)

typedef __attribute__((ext_vector_type(8))) short bf16x8;
typedef __attribute__((ext_vector_type(4))) short short4v;
typedef __attribute__((ext_vector_type(4))) float f32x4;

__device__ inline short f2bf(float f) {
    union { float f; unsigned u; } v; v.f = f;
    unsigned r = v.u + 0x7fff + ((v.u >> 16) & 1);  // RNE
    return (short)(r >> 16);
}

__device__ inline f32x4 mfma16(bf16x8 a, bf16x8 b, f32x4 c) {
    return __builtin_amdgcn_mfma_f32_16x16x32_bf16(a, b, c, 0, 0, 0);
}

__device__ __forceinline__ void gload16(const void* g, void* l) {
    __builtin_amdgcn_global_load_lds(
        (const __attribute__((address_space(1))) unsigned int*)g,
        (__attribute__((address_space(3))) unsigned int*)l, 16, 0, 0);
}

// ---------------------------------------------------------------------------
// 1. scan: seg=cumsum(done), total, aux[0..31]=segment-start tile per t-tile,
//    aux[32]=first chunk containing a last-segment token
// ---------------------------------------------------------------------------
__global__ __launch_bounds__(256) void scan_kernel(const int* __restrict__ done,
                                                   int* __restrict__ seg,
                                                   int* __restrict__ totalp,
                                                   int* __restrict__ aux) {
    __shared__ int part[256];
    __shared__ int excl[256];
    __shared__ int segl[2048];
    __shared__ int tot;
    int tid = threadIdx.x;
    int base = tid * 8;
    int local[8];
    int run = 0;
#pragma unroll
    for (int i = 0; i < 8; ++i) { run += (done[base + i] != 0) ? 1 : 0; local[i] = run; }
    part[tid] = run;
    __syncthreads();
    if (tid < 64) {
        int p4[4];
#pragma unroll
        for (int i = 0; i < 4; ++i) p4[i] = part[tid * 4 + i];
        int s = p4[0] + p4[1] + p4[2] + p4[3];
        int v = s;
#pragma unroll
        for (int off = 1; off < 64; off <<= 1) {
            int u = __shfl_up(v, off);
            if (tid >= off) v += u;
        }
        int ex = v - s;
#pragma unroll
        for (int i = 0; i < 4; ++i) { excl[tid * 4 + i] = ex; ex += p4[i]; }
        if (tid == 63) { totalp[0] = v; tot = v; }
    }
    __syncthreads();
    int off = excl[tid];
#pragma unroll
    for (int i = 0; i < 8; ++i) {
        int sv = off + local[i];
        seg[base + i] = sv;
        segl[base + i] = sv;
    }
    __syncthreads();
    if (tid < 33) {
        int target = (tid < 32) ? segl[tid * 64] : tot;
        int lo = 0, hi = 2047;
        while (lo < hi) { int mid = (lo + hi) >> 1; if (segl[mid] >= target) hi = mid; else lo = mid + 1; }
        aux[tid] = lo >> 6;
    }
}

// ---------------------------------------------------------------------------
// 2. prep: x cast, weight transposes, state transpose, state-output init
// ---------------------------------------------------------------------------
__device__ void transpose_tile(const float* __restrict__ in, short* __restrict__ out,
                               int R, int C, int r0, int c0, float (*tile)[65]) {
    int tid = threadIdx.x;
#pragma unroll
    for (int p = 0; p < 4; ++p) {
        int ch = tid + p * 256;
        int r = ch >> 4, c4 = (ch & 15) * 4;
        float4 v = *(const float4*)&in[(size_t)(r0 + r) * C + c0 + c4];
        tile[r][c4] = v.x; tile[r][c4 + 1] = v.y; tile[r][c4 + 2] = v.z; tile[r][c4 + 3] = v.w;
    }
    __syncthreads();
#pragma unroll
    for (int p = 0; p < 2; ++p) {
        int ch = tid + p * 256;
        int c = ch >> 3, r8 = (ch & 7) * 8;
        short tmp[8];
#pragma unroll
        for (int i = 0; i < 8; ++i) tmp[i] = f2bf(tile[r8 + i][c]);
        *(float4*)&out[(size_t)(c0 + c) * R + r0 + r8] = *(float4*)tmp;
    }
}

__global__ __launch_bounds__(256) void prep_kernel(const float* __restrict__ x,
                                                   const float* __restrict__ w_qkv,
                                                   const float* __restrict__ w_out,
                                                   const float* __restrict__ state,
                                                   const int* __restrict__ totalp,
                                                   short* __restrict__ x_bf,
                                                   short* __restrict__ wqT,
                                                   short* __restrict__ woT,
                                                   short* __restrict__ stT,
                                                   float* __restrict__ stout) {
    __shared__ float tile[64][65];
    int b = blockIdx.x;
    if (b < 1024) {
        int i = (b * 256 + threadIdx.x) * 8;
        float4 a = *(const float4*)&x[i];
        float4 c = *(const float4*)&x[i + 4];
        short tmp[8] = {f2bf(a.x), f2bf(a.y), f2bf(a.z), f2bf(a.w),
                        f2bf(c.x), f2bf(c.y), f2bf(c.z), f2bf(c.w)};
        *(float4*)&x_bf[i] = *(float4*)tmp;
    } else if (b < 1792) {
        int bb = b - 1024;
        transpose_tile(w_qkv, wqT, DD, QKV_N, (bb & 15) * 64, (bb >> 4) * 64, tile);
    } else if (b < 2048) {
        int bb = b - 1792;
        transpose_tile(w_out, woT, DD, DD, (bb & 15) * 64, (bb >> 4) * 64, tile);
    } else if (b < 2064) {
        int h = b - 2048;
        transpose_tile(state + (size_t)h * 4096, stT + (size_t)h * 4096, DH, DH, 0, 0, tile);
    } else {
        // init new_state output: done_any ? 0 : state  (state_mfma atomicAdds on top)
        int f = ((b - 2064) * 256 + threadIdx.x) * 4;
        bool done_any = totalp[0] > 0;
        float4 v = done_any ? make_float4(0.f, 0.f, 0.f, 0.f) : *(const float4*)&state[f];
        *(float4*)&stout[f] = v;
    }
}

// ---------------------------------------------------------------------------
// 3. QKV GEMM (m97 pattern) with region epilogue:
//    cols <2048 -> qk[t][col] (Q,K natural); cols >=2048 -> vt[h][e][t] packed
// ---------------------------------------------------------------------------
__global__ __launch_bounds__(256) void gemm_qkv(const short* __restrict__ A,
                                                const short* __restrict__ BT,
                                                const float* __restrict__ bias,
                                                short* __restrict__ qk,
                                                short* __restrict__ vt) {
    __shared__ short As[128 * 32];
    __shared__ short Bs[128 * 32];
    const int K = DD, N = QKV_N;
    int tid = threadIdx.x;
    int wave = tid >> 6, lane = tid & 63;
    int quad = lane >> 4, l15 = lane & 15;
    int m0 = blockIdx.x * 128, n0 = blockIdx.y * 128;
    int wr = (wave >> 1) * 64, wc = (wave & 1) * 64;

    int srow = wave * 16 + (lane >> 2);
    int scol = (lane & 3) * 8;
    const short* Ag = A + (size_t)(m0 + srow) * K + scol;
    const short* Bg = BT + (size_t)(n0 + srow) * K + scol;
    short* As0 = &As[(wave * 16) * 32];
    short* As1 = &As[(64 + wave * 16) * 32];
    short* Bs0 = &Bs[(wave * 16) * 32];
    short* Bs1 = &Bs[(64 + wave * 16) * 32];

    f32x4 acc[4][4] = {};
    for (int k0 = 0; k0 < K; k0 += 32) {
        __syncthreads();
        gload16(Ag + k0, As0);
        gload16(Ag + (size_t)64 * K + k0, As1);
        gload16(Bg + k0, Bs0);
        gload16(Bg + (size_t)64 * K + k0, Bs1);
        __syncthreads();
        bf16x8 af[4], bfr[4];
#pragma unroll
        for (int i = 0; i < 4; ++i) {
            af[i]  = *(const bf16x8*)&As[(wr + i * 16 + l15) * 32 + quad * 8];
            bfr[i] = *(const bf16x8*)&Bs[(wc + i * 16 + l15) * 32 + quad * 8];
        }
#pragma unroll
        for (int i = 0; i < 4; ++i)
#pragma unroll
            for (int j = 0; j < 4; ++j)
                acc[i][j] = mfma16(af[i], bfr[j], acc[i][j]);
    }

    if (n0 < 2048) {
#pragma unroll
        for (int i = 0; i < 4; ++i)
#pragma unroll
            for (int j = 0; j < 4; ++j)
#pragma unroll
                for (int r = 0; r < 4; ++r) {
                    int row = m0 + wr + i * 16 + quad * 4 + r;
                    int col = n0 + wc + j * 16 + l15;
                    qk[(size_t)row * QKW + col] = f2bf(acc[i][j][r] + bias[col]);
                }
    } else {
#pragma unroll
        for (int j = 0; j < 4; ++j) {
            int col = n0 + wc + j * 16 + l15;
            float bv = bias[col];
            int eg = col - 2048;
            int hh = eg >> 6, e = eg & 63;
#pragma unroll
            for (int i = 0; i < 4; ++i) {
                int tb = m0 + wr + i * 16 + quad * 4;
                short4v pk;
#pragma unroll
                for (int r = 0; r < 4; ++r) pk[r] = f2bf(acc[i][j][r] + bv);
                *(short4v*)&vt[(size_t)hh * (DH * TT) + (size_t)e * TT + tb] = pk;
            }
        }
    }
}

// ---------------------------------------------------------------------------
// 4. attention — barrier-free. block=(h, t-tile 64), 4 waves, wave owns a
//    16-row t-strip. Q/K/stateT frags direct from global; V from vt; the
//    masked-S round-trip uses a wave-PRIVATE LDS strip (no __syncthreads).
//    Accumulates out^T: accT[j] covers e=j*16+quad*4+r, t=myt+l15.
// ---------------------------------------------------------------------------
__global__ __launch_bounds__(256) void attn_mfma(const short* __restrict__ qk,
                                                 const short* __restrict__ vt,
                                                 const short* __restrict__ stT,
                                                 const int* __restrict__ seg,
                                                 const int* __restrict__ aux,
                                                 short* __restrict__ outb) {
    __shared__ short Ss_lo[64 * 32];  // [t-local][s 0..31]
    __shared__ short Ss_hi[64 * 32];  // [t-local][s 32..63]

    int h = blockIdx.x, tt = blockIdx.y;
    int t0 = tt * 64;
    int tid = threadIdx.x, wave = tid >> 6, lane = tid & 63;
    int quad = lane >> 4, l15 = lane & 15;
    int myt = wave * 16;

    // Q fragments (A-layout, lane row = myt+l15), reused everywhere
    const short* qrow = qk + (size_t)(t0 + myt + l15) * QKW + h * DH + quad * 8;
    bf16x8 qf0 = *(const bf16x8*)qrow;
    bf16x8 qf1 = *(const bf16x8*)(qrow + 32);

    int tlane = t0 + myt + l15;            // this lane's t column in out^T
    int seg_lane = seg[tlane];
    int segt_r[4];
#pragma unroll
    for (int r = 0; r < 4; ++r) segt_r[r] = seg[t0 + myt + quad * 4 + r];

    f32x4 accT[4] = {};
    if (seg[t0] == 0) {
        const short* sb = stT + (size_t)h * 4096;  // [e][d]
#pragma unroll
        for (int j = 0; j < 4; ++j) {
            const short* srow = sb + (j * 16 + l15) * 64 + quad * 8;
            bf16x8 a0 = *(const bf16x8*)srow;
            bf16x8 a1 = *(const bf16x8*)(srow + 32);
            accT[j] = mfma16(a0, qf0, accT[j]);
            accT[j] = mfma16(a1, qf1, accT[j]);
        }
        if (seg_lane != 0) {
#pragma unroll
            for (int j = 0; j < 4; ++j)
#pragma unroll
                for (int r = 0; r < 4; ++r) accT[j][r] = 0.f;
        }
    }

    short* ss_lo = &Ss_lo[myt * 32];  // wave-private 16 rows
    short* ss_hi = &Ss_hi[myt * 32];
    const short* kbase = qk + 1024 + h * DH;
    const short* vbase = vt + (size_t)h * (DH * TT);

    int st0 = aux[tt];
    for (int st = st0; st <= tt; ++st) {
        int s0 = st * 64;
        // S = Q K^T for this wave's 16-t strip (D[t][s]: rows=quad*4+r, cols=j*16+l15)
        f32x4 sacc[4] = {};
#pragma unroll
        for (int j = 0; j < 4; ++j) {
            const short* krow = kbase + (size_t)(s0 + j * 16 + l15) * QKW + quad * 8;
            bf16x8 b0 = *(const bf16x8*)krow;
            bf16x8 b1 = *(const bf16x8*)(krow + 32);
            sacc[j] = mfma16(qf0, b0, sacc[j]);
            sacc[j] = mfma16(qf1, b1, sacc[j]);
        }
        // mask + store to wave-private Ss (j<2 -> lo, j>=2 -> hi, compile-time)
        bool last = (st == tt);
#pragma unroll
        for (int j = 0; j < 4; ++j) {
            int sgl = s0 + j * 16 + l15;
            int seg_s = seg[sgl];
#pragma unroll
            for (int r = 0; r < 4; ++r) {
                bool ok = (seg_s == segt_r[r]);
                if (last) ok = ok && (sgl <= t0 + myt + quad * 4 + r);
                short v = ok ? f2bf(sacc[j][r]) : (short)0;
                int row = quad * 4 + r;
                if (j < 2) ss_lo[row * 32 + j * 16 + l15] = v;
                else       ss_hi[row * 32 + (j - 2) * 16 + l15] = v;
            }
        }
        // S@V transposed: accT[e-block j][t=l15] += Vt-frag * Ss-frag
        bf16x8 sf0 = *(const bf16x8*)&ss_lo[l15 * 32 + quad * 8];
        bf16x8 sf1 = *(const bf16x8*)&ss_hi[l15 * 32 + quad * 8];
#pragma unroll
        for (int j = 0; j < 4; ++j) {
            const short* vrow = vbase + (size_t)(j * 16 + l15) * TT + s0 + quad * 8;
            bf16x8 a0 = *(const bf16x8*)vrow;
            bf16x8 a1 = *(const bf16x8*)(vrow + 32);
            accT[j] = mfma16(a0, sf0, accT[j]);
            accT[j] = mfma16(a1, sf1, accT[j]);
        }
    }

    // epilogue: outb[t][h*64+e], 4 consecutive e per (j) -> 8B packed stores
#pragma unroll
    for (int j = 0; j < 4; ++j) {
        short4v pk;
#pragma unroll
        for (int r = 0; r < 4; ++r) pk[r] = f2bf(accT[j][r]);
        *(short4v*)&outb[(size_t)tlane * DD + h * DH + j * 16 + quad * 4] = pk;
    }
}

// ---------------------------------------------------------------------------
// 5. state partials: atomicAdd (done by active chunks) onto prep-initialized
//    new_state. Wave-private K^T scatter; V^T frags direct from vt.
// ---------------------------------------------------------------------------
__global__ __launch_bounds__(256) void state_mfma(const short* __restrict__ qk,
                                                  const short* __restrict__ vt,
                                                  const int* __restrict__ seg,
                                                  const int* __restrict__ totalp,
                                                  const int* __restrict__ aux,
                                                  float* __restrict__ out) {
    __shared__ short Kt_lo[64 * 32];  // [d][t 0..31]
    __shared__ short Kt_hi[64 * 32];  // [d][t 32..63]
    int h = blockIdx.x, ct = blockIdx.y;
    if (ct < aux[32]) return;
    int t0 = ct * 64;
    int total = totalp[0];
    int tid = threadIdx.x, wave = tid >> 6, lane = tid & 63;
    int quad = lane >> 4, l15 = lane & 15;
    int myd = wave * 16;

    // scatter: lane handles t=lane, d = myd..myd+15 (keeps Kt rows wave-private)
    {
        bool keep = (seg[t0 + lane] == total);
        const short* src = qk + (size_t)(t0 + lane) * QKW + 1024 + h * DH + myd;
        union { float4 f; short s[8]; } u0, u1;
        u0.f = keep ? *(const float4*)src : make_float4(0.f, 0.f, 0.f, 0.f);
        u1.f = keep ? *(const float4*)(src + 8) : make_float4(0.f, 0.f, 0.f, 0.f);
        short* dst = (lane < 32) ? &Kt_lo[lane] : &Kt_hi[lane - 32];
#pragma unroll
        for (int i = 0; i < 8; ++i) {
            dst[(myd + i) * 32] = u0.s[i];
            dst[(myd + 8 + i) * 32] = u1.s[i];
        }
    }
    // A-frags: K^T[d][t], wave-private rows
    bf16x8 a0 = *(const bf16x8*)&Kt_lo[(myd + l15) * 32 + quad * 8];
    bf16x8 a1 = *(const bf16x8*)&Kt_hi[(myd + l15) * 32 + quad * 8];

    const short* vbase = vt + (size_t)h * (DH * TT);
    f32x4 acc[4] = {};
#pragma unroll
    for (int j = 0; j < 4; ++j) {
        const short* vrow = vbase + (size_t)(j * 16 + l15) * TT + t0 + quad * 8;
        bf16x8 b0 = *(const bf16x8*)vrow;
        bf16x8 b1 = *(const bf16x8*)(vrow + 32);
        acc[j] = mfma16(a0, b0, acc[j]);
        acc[j] = mfma16(a1, b1, acc[j]);
    }
    float* oh = out + (size_t)h * 4096;
#pragma unroll
    for (int j = 0; j < 4; ++j)
#pragma unroll
        for (int r = 0; r < 4; ++r)
            atomicAdd(&oh[(myd + quad * 4 + r) * DH + j * 16 + l15], acc[j][r]);
}

// ---------------------------------------------------------------------------
// 6. generic bf16 GEMM (out-proj), unchanged from round 4
// ---------------------------------------------------------------------------
__global__ __launch_bounds__(256) void gemm_out(const short* __restrict__ A,
                                                const short* __restrict__ BT,
                                                const float* __restrict__ bias,
                                                float* __restrict__ Cout,
                                                int M, int N, int K) {
    __shared__ short As[128 * 32];
    __shared__ short Bs[128 * 32];
    int tid = threadIdx.x;
    int wave = tid >> 6, lane = tid & 63;
    int quad = lane >> 4, l15 = lane & 15;
    int m0 = blockIdx.x * 128, n0 = blockIdx.y * 128;
    int wr = (wave >> 1) * 64, wc = (wave & 1) * 64;

    int srow = wave * 16 + (lane >> 2);
    int scol = (lane & 3) * 8;
    const short* Ag = A + (size_t)(m0 + srow) * K + scol;
    const short* Bg = BT + (size_t)(n0 + srow) * K + scol;
    short* As0 = &As[(wave * 16) * 32];
    short* As1 = &As[(64 + wave * 16) * 32];
    short* Bs0 = &Bs[(wave * 16) * 32];
    short* Bs1 = &Bs[(64 + wave * 16) * 32];

    f32x4 acc[4][4] = {};
    for (int k0 = 0; k0 < K; k0 += 32) {
        __syncthreads();
        gload16(Ag + k0, As0);
        gload16(Ag + (size_t)64 * K + k0, As1);
        gload16(Bg + k0, Bs0);
        gload16(Bg + (size_t)64 * K + k0, Bs1);
        __syncthreads();
        bf16x8 af[4], bfr[4];
#pragma unroll
        for (int i = 0; i < 4; ++i) {
            af[i]  = *(const bf16x8*)&As[(wr + i * 16 + l15) * 32 + quad * 8];
            bfr[i] = *(const bf16x8*)&Bs[(wc + i * 16 + l15) * 32 + quad * 8];
        }
#pragma unroll
        for (int i = 0; i < 4; ++i)
#pragma unroll
            for (int j = 0; j < 4; ++j)
                acc[i][j] = mfma16(af[i], bfr[j], acc[i][j]);
    }
#pragma unroll
    for (int i = 0; i < 4; ++i)
#pragma unroll
        for (int j = 0; j < 4; ++j)
#pragma unroll
            for (int r = 0; r < 4; ++r) {
                int row = m0 + wr + i * 16 + quad * 4 + r;
                int col = n0 + wc + j * 16 + l15;
                Cout[(size_t)row * N + col] = acc[i][j][r] + bias[col];
            }
}

// ---------------------------------------------------------------------------
// Host launcher
// ---------------------------------------------------------------------------
extern "C" void kernel_launch(void* const* d_in, const int* in_sizes, int n_in,
                              void* d_out, int out_size, void* d_ws, size_t ws_size,
                              hipStream_t stream) {
    const float* state = (const float*)d_in[0];
    const float* x     = (const float*)d_in[1];
    const int*   done  = (const int*)d_in[2];
    const float* w_qkv = (const float*)d_in[3];
    const float* b_qkv = (const float*)d_in[4];
    const float* w_out = (const float*)d_in[5];
    const float* b_out = (const float*)d_in[6];

    char* ws = (char*)d_ws;
    int*   seg    = (int*)ws;                         // 8 KB
    int*   totalp = (int*)(ws + 8192);
    int*   aux    = (int*)(ws + 8256);                // 33 ints
    short* wqT    = (short*)(ws + 8448);              // 6 MB   [3072][1024]
    short* woT    = (short*)(ws + 6299904);           // 2 MB   [1024][1024]
    short* stT    = (short*)(ws + 8397056);           // 128 KB [h][e][d]
    short* qk     = (short*)(ws + 8528128);           // 8 MB   [T][2048] (Q|K)
    short* vt     = (short*)(ws + 16916736);          // 4 MB   [h][e][T]
    short* xbf_outb = (short*)(ws + 21111040);        // 4 MB   x_bf then outb
    // total 25,305,344 B

    float* new_state_out = (float*)d_out;
    float* x_out         = (float*)d_out + HH * DH * DH;

    scan_kernel<<<1, 256, 0, stream>>>(done, seg, totalp, aux);
    prep_kernel<<<2128, 256, 0, stream>>>(x, w_qkv, w_out, state, totalp,
                                          xbf_outb, wqT, woT, stT, new_state_out);

    gemm_qkv<<<dim3(TT / 128, QKV_N / 128), 256, 0, stream>>>(
        xbf_outb, wqT, b_qkv, qk, vt);

    attn_mfma<<<dim3(HH, TT / 64), 256, 0, stream>>>(qk, vt, stT, seg, aux, xbf_outb);

    state_mfma<<<dim3(HH, TT / 64), 256, 0, stream>>>(qk, vt, seg, totalp, aux,
                                                      new_state_out);

    gemm_out<<<dim3(TT / 128, DD / 128), 256, 0, stream>>>(
        xbf_outb, woT, b_out, x_out, TT, DD, DD);
}

// Round 6
// 180.309 us; speedup vs baseline: 1.1015x; 1.0147x over previous
//
#include <hip/hip_runtime.h>

#define TT 2048
#define DD 1024
#define HH 16
#define DH 64
#define QKV_N 3072
#define QKW 2048  // qk buffer width (Q cols 0..1023, K cols 1024..2047)

typedef __attribute__((ext_vector_type(8))) short bf16x8;
typedef __attribute__((ext_vector_type(4))) short short4v;
typedef __attribute__((ext_vector_type(4))) float f32x4;

__device__ inline short f2bf(float f) {
    union { float f; unsigned u; } v; v.f = f;
    unsigned r = v.u + 0x7fff + ((v.u >> 16) & 1);  // RNE
    return (short)(r >> 16);
}

__device__ inline f32x4 mfma16(bf16x8 a, bf16x8 b, f32x4 c) {
    return __builtin_amdgcn_mfma_f32_16x16x32_bf16(a, b, c, 0, 0, 0);
}

__device__ __forceinline__ void gload16(const void* g, void* l) {
    __builtin_amdgcn_global_load_lds(
        (const __attribute__((address_space(1))) unsigned int*)g,
        (__attribute__((address_space(3))) unsigned int*)l, 16, 0, 0);
}

// ---------------------------------------------------------------------------
// 1. prep: x cast, weight/state transposes, new_state init, scan (block 2128)
// ---------------------------------------------------------------------------
__device__ void transpose_tile(const float* __restrict__ in, short* __restrict__ out,
                               int R, int C, int r0, int c0, float (*tile)[65]) {
    int tid = threadIdx.x;
#pragma unroll
    for (int p = 0; p < 4; ++p) {
        int ch = tid + p * 256;
        int r = ch >> 4, c4 = (ch & 15) * 4;
        float4 v = *(const float4*)&in[(size_t)(r0 + r) * C + c0 + c4];
        tile[r][c4] = v.x; tile[r][c4 + 1] = v.y; tile[r][c4 + 2] = v.z; tile[r][c4 + 3] = v.w;
    }
    __syncthreads();
#pragma unroll
    for (int p = 0; p < 2; ++p) {
        int ch = tid + p * 256;
        int c = ch >> 3, r8 = (ch & 7) * 8;
        short tmp[8];
#pragma unroll
        for (int i = 0; i < 8; ++i) tmp[i] = f2bf(tile[r8 + i][c]);
        *(float4*)&out[(size_t)(c0 + c) * R + r0 + r8] = *(float4*)tmp;
    }
}

__global__ __launch_bounds__(256) void prep_kernel(const float* __restrict__ x,
                                                   const float* __restrict__ w_qkv,
                                                   const float* __restrict__ w_out,
                                                   const float* __restrict__ state,
                                                   const int* __restrict__ done,
                                                   short* __restrict__ x_bf,
                                                   short* __restrict__ wqT,
                                                   short* __restrict__ woT,
                                                   short* __restrict__ stT,
                                                   float* __restrict__ stout,
                                                   int* __restrict__ seg,
                                                   int* __restrict__ totalp,
                                                   int* __restrict__ aux) {
    __shared__ float tile[64][65];
    __shared__ int scanbuf[2048 + 512 + 1];  // segl | part | excl | tot
    int b = blockIdx.x;
    int tid = threadIdx.x;
    if (b < 1024) {
        int i = (b * 256 + tid) * 8;
        float4 a = *(const float4*)&x[i];
        float4 c = *(const float4*)&x[i + 4];
        short tmp[8] = {f2bf(a.x), f2bf(a.y), f2bf(a.z), f2bf(a.w),
                        f2bf(c.x), f2bf(c.y), f2bf(c.z), f2bf(c.w)};
        *(float4*)&x_bf[i] = *(float4*)tmp;
    } else if (b < 1792) {
        int bb = b - 1024;
        transpose_tile(w_qkv, wqT, DD, QKV_N, (bb & 15) * 64, (bb >> 4) * 64, tile);
    } else if (b < 2048) {
        int bb = b - 1792;
        transpose_tile(w_out, woT, DD, DD, (bb & 15) * 64, (bb >> 4) * 64, tile);
    } else if (b < 2064) {
        int h = b - 2048;
        transpose_tile(state + (size_t)h * 4096, stT + (size_t)h * 4096, DH, DH, 0, 0, tile);
    } else if (b < 2128) {
        // init new_state output: done_any ? 0 : state  (attn sc=4 atomicAdds on top)
        __shared__ int anyf;
        if (tid == 0) anyf = 0;
        __syncthreads();
        int acc = 0;
#pragma unroll
        for (int i = 0; i < 8; ++i) acc |= done[tid * 8 + i];
        if (acc) anyf = 1;
        __syncthreads();
        int f = ((b - 2064) * 256 + tid) * 4;
        float4 v = anyf ? make_float4(0.f, 0.f, 0.f, 0.f) : *(const float4*)&state[f];
        *(float4*)&stout[f] = v;
    } else {
        // scan: seg=cumsum(done), total, aux
        int* segl = scanbuf;
        int* part = scanbuf + 2048;
        int* excl = scanbuf + 2304;
        int base = tid * 8;
        int local[8];
        int run = 0;
#pragma unroll
        for (int i = 0; i < 8; ++i) { run += (done[base + i] != 0) ? 1 : 0; local[i] = run; }
        part[tid] = run;
        __syncthreads();
        if (tid < 64) {
            int p4[4];
#pragma unroll
            for (int i = 0; i < 4; ++i) p4[i] = part[tid * 4 + i];
            int s = p4[0] + p4[1] + p4[2] + p4[3];
            int v = s;
#pragma unroll
            for (int off = 1; off < 64; off <<= 1) {
                int u = __shfl_up(v, off);
                if (tid >= off) v += u;
            }
            int ex = v - s;
#pragma unroll
            for (int i = 0; i < 4; ++i) { excl[tid * 4 + i] = ex; ex += p4[i]; }
            if (tid == 63) { totalp[0] = v; scanbuf[2560] = v; }
        }
        __syncthreads();
        int off = excl[tid];
#pragma unroll
        for (int i = 0; i < 8; ++i) {
            int sv = off + local[i];
            seg[base + i] = sv;
            segl[base + i] = sv;
        }
        __syncthreads();
        if (tid < 33) {
            int target = (tid < 32) ? segl[tid * 64] : scanbuf[2560];
            int lo = 0, hi = 2047;
            while (lo < hi) { int mid = (lo + hi) >> 1; if (segl[mid] >= target) hi = mid; else lo = mid + 1; }
            aux[tid] = lo >> 6;
        }
    }
}

// ---------------------------------------------------------------------------
// 2. QKV GEMM (m97 pattern): cols <2048 -> qk natural; cols >=2048 -> vt[h][e][t]
// ---------------------------------------------------------------------------
__global__ __launch_bounds__(256) void gemm_qkv(const short* __restrict__ A,
                                                const short* __restrict__ BT,
                                                const float* __restrict__ bias,
                                                short* __restrict__ qk,
                                                short* __restrict__ vt) {
    __shared__ short As[128 * 32];
    __shared__ short Bs[128 * 32];
    const int K = DD;
    int tid = threadIdx.x;
    int wave = tid >> 6, lane = tid & 63;
    int quad = lane >> 4, l15 = lane & 15;
    int m0 = blockIdx.x * 128, n0 = blockIdx.y * 128;
    int wr = (wave >> 1) * 64, wc = (wave & 1) * 64;

    int srow = wave * 16 + (lane >> 2);
    int scol = (lane & 3) * 8;
    const short* Ag = A + (size_t)(m0 + srow) * K + scol;
    const short* Bg = BT + (size_t)(n0 + srow) * K + scol;
    short* As0 = &As[(wave * 16) * 32];
    short* As1 = &As[(64 + wave * 16) * 32];
    short* Bs0 = &Bs[(wave * 16) * 32];
    short* Bs1 = &Bs[(64 + wave * 16) * 32];

    f32x4 acc[4][4] = {};
    for (int k0 = 0; k0 < K; k0 += 32) {
        __syncthreads();
        gload16(Ag + k0, As0);
        gload16(Ag + (size_t)64 * K + k0, As1);
        gload16(Bg + k0, Bs0);
        gload16(Bg + (size_t)64 * K + k0, Bs1);
        __syncthreads();
        bf16x8 af[4], bfr[4];
#pragma unroll
        for (int i = 0; i < 4; ++i) {
            af[i]  = *(const bf16x8*)&As[(wr + i * 16 + l15) * 32 + quad * 8];
            bfr[i] = *(const bf16x8*)&Bs[(wc + i * 16 + l15) * 32 + quad * 8];
        }
#pragma unroll
        for (int i = 0; i < 4; ++i)
#pragma unroll
            for (int j = 0; j < 4; ++j)
                acc[i][j] = mfma16(af[i], bfr[j], acc[i][j]);
    }

    if (n0 < 2048) {
#pragma unroll
        for (int i = 0; i < 4; ++i)
#pragma unroll
            for (int j = 0; j < 4; ++j)
#pragma unroll
                for (int r = 0; r < 4; ++r) {
                    int row = m0 + wr + i * 16 + quad * 4 + r;
                    int col = n0 + wc + j * 16 + l15;
                    qk[(size_t)row * QKW + col] = f2bf(acc[i][j][r] + bias[col]);
                }
    } else {
#pragma unroll
        for (int j = 0; j < 4; ++j) {
            int col = n0 + wc + j * 16 + l15;
            float bv = bias[col];
            int eg = col - 2048;
            int hh = eg >> 6, e = eg & 63;
#pragma unroll
            for (int i = 0; i < 4; ++i) {
                int tb = m0 + wr + i * 16 + quad * 4;
                short4v pk;
#pragma unroll
                for (int r = 0; r < 4; ++r) pk[r] = f2bf(acc[i][j][r] + bv);
                *(short4v*)&vt[(size_t)hh * (DH * TT) + (size_t)e * TT + tb] = pk;
            }
        }
    }
}

// ---------------------------------------------------------------------------
// 3. attention — s-chunked, barrier-free. grid (H, tt, sc: 0..3 attn, 4 state)
//    sc chunk covers s-tiles [sc*8, sc*8+7] ∩ [aux[tt], tt]. Single-chunk
//    ranges write outb directly; multi-chunk write fp32 partials.
// ---------------------------------------------------------------------------
__global__ __launch_bounds__(256) void attn_mfma(const short* __restrict__ qk,
                                                 const short* __restrict__ vt,
                                                 const short* __restrict__ stT,
                                                 const int* __restrict__ seg,
                                                 const int* __restrict__ totalp,
                                                 const int* __restrict__ aux,
                                                 short* __restrict__ outb,
                                                 float* __restrict__ part,
                                                 float* __restrict__ nsout) {
    __shared__ short Ss_lo[64 * 32];
    __shared__ short Ss_hi[64 * 32];

    int h = blockIdx.x, tt = blockIdx.y, sc = blockIdx.z;
    int t0 = tt * 64;
    int tid = threadIdx.x, wave = tid >> 6, lane = tid & 63;
    int quad = lane >> 4, l15 = lane & 15;
    int myt = wave * 16;
    const short* vbase = vt + (size_t)h * (DH * TT);

    if (sc == 4) {
        // ---- state update path (ct = tt), atomicAdd onto prep-initialized nsout
        if (tt < aux[32]) return;
        int total = totalp[0];
        int myd = myt;
        {
            bool keep = (seg[t0 + lane] == total);
            const short* src = qk + (size_t)(t0 + lane) * QKW + 1024 + h * DH + myd;
            union { float4 f; short s[8]; } u0, u1;
            u0.f = keep ? *(const float4*)src : make_float4(0.f, 0.f, 0.f, 0.f);
            u1.f = keep ? *(const float4*)(src + 8) : make_float4(0.f, 0.f, 0.f, 0.f);
            short* dst = (lane < 32) ? &Ss_lo[lane] : &Ss_hi[lane - 32];
#pragma unroll
            for (int i = 0; i < 8; ++i) {
                dst[(myd + i) * 32] = u0.s[i];
                dst[(myd + 8 + i) * 32] = u1.s[i];
            }
        }
        bf16x8 a0 = *(const bf16x8*)&Ss_lo[(myd + l15) * 32 + quad * 8];
        bf16x8 a1 = *(const bf16x8*)&Ss_hi[(myd + l15) * 32 + quad * 8];
        f32x4 acc[4] = {};
#pragma unroll
        for (int j = 0; j < 4; ++j) {
            const short* vrow = vbase + (size_t)(j * 16 + l15) * TT + t0 + quad * 8;
            bf16x8 b0 = *(const bf16x8*)vrow;
            bf16x8 b1 = *(const bf16x8*)(vrow + 32);
            acc[j] = mfma16(a0, b0, acc[j]);
            acc[j] = mfma16(a1, b1, acc[j]);
        }
        float* oh = nsout + (size_t)h * 4096;
#pragma unroll
        for (int j = 0; j < 4; ++j)
#pragma unroll
            for (int r = 0; r < 4; ++r)
                atomicAdd(&oh[(myd + quad * 4 + r) * DH + j * 16 + l15], acc[j][r]);
        return;
    }

    int st0 = aux[tt];
    int sc_lo = st0 >> 3, sc_hi = tt >> 3;
    if (sc < sc_lo || sc > sc_hi) return;
    bool direct = (sc_lo == sc_hi);
    int st_lo = (st0 > sc * 8) ? st0 : sc * 8;
    int st_hi = (tt < sc * 8 + 7) ? tt : sc * 8 + 7;

    // Q fragments (A-layout row = myt+l15)
    const short* qrow = qk + (size_t)(t0 + myt + l15) * QKW + h * DH + quad * 8;
    bf16x8 qf0 = *(const bf16x8*)qrow;
    bf16x8 qf1 = *(const bf16x8*)(qrow + 32);

    int tlane = t0 + myt + l15;
    int seg_lane = seg[tlane];
    int segt_r[4];
#pragma unroll
    for (int r = 0; r < 4; ++r) segt_r[r] = seg[t0 + myt + quad * 4 + r];

    f32x4 accT[4] = {};
    if (sc == sc_lo && seg[t0] == 0) {
        const short* sb = stT + (size_t)h * 4096;  // [e][d]
#pragma unroll
        for (int j = 0; j < 4; ++j) {
            const short* srow = sb + (j * 16 + l15) * 64 + quad * 8;
            bf16x8 a0 = *(const bf16x8*)srow;
            bf16x8 a1 = *(const bf16x8*)(srow + 32);
            accT[j] = mfma16(a0, qf0, accT[j]);
            accT[j] = mfma16(a1, qf1, accT[j]);
        }
        if (seg_lane != 0) {
#pragma unroll
            for (int j = 0; j < 4; ++j)
#pragma unroll
                for (int r = 0; r < 4; ++r) accT[j][r] = 0.f;
        }
    }

    short* ss_lo = &Ss_lo[myt * 32];  // wave-private 16 rows
    short* ss_hi = &Ss_hi[myt * 32];
    const short* kbase = qk + 1024 + h * DH;

    for (int st = st_lo; st <= st_hi; ++st) {
        int s0 = st * 64;
        int segv[4];
#pragma unroll
        for (int j = 0; j < 4; ++j) segv[j] = seg[s0 + j * 16 + l15];
        // K fragments
        bf16x8 kb0[4], kb1[4];
#pragma unroll
        for (int j = 0; j < 4; ++j) {
            const short* krow = kbase + (size_t)(s0 + j * 16 + l15) * QKW + quad * 8;
            kb0[j] = *(const bf16x8*)krow;
            kb1[j] = *(const bf16x8*)(krow + 32);
        }
        // V fragments (independent of S — issue early)
        bf16x8 va0[4], va1[4];
#pragma unroll
        for (int j = 0; j < 4; ++j) {
            const short* vrow = vbase + (size_t)(j * 16 + l15) * TT + s0 + quad * 8;
            va0[j] = *(const bf16x8*)vrow;
            va1[j] = *(const bf16x8*)(vrow + 32);
        }
        // S = Q K^T
        f32x4 sacc[4] = {};
#pragma unroll
        for (int j = 0; j < 4; ++j) {
            sacc[j] = mfma16(qf0, kb0[j], sacc[j]);
            sacc[j] = mfma16(qf1, kb1[j], sacc[j]);
        }
        // mask + wave-private LDS round trip (C-layout -> A/B-layout)
        bool last = (st == tt);
#pragma unroll
        for (int j = 0; j < 4; ++j) {
            int sgl = s0 + j * 16 + l15;
#pragma unroll
            for (int r = 0; r < 4; ++r) {
                bool ok = (segv[j] == segt_r[r]);
                if (last) ok = ok && (sgl <= t0 + myt + quad * 4 + r);
                short v = ok ? f2bf(sacc[j][r]) : (short)0;
                int row = quad * 4 + r;
                if (j < 2) ss_lo[row * 32 + j * 16 + l15] = v;
                else       ss_hi[row * 32 + (j - 2) * 16 + l15] = v;
            }
        }
        bf16x8 sf0 = *(const bf16x8*)&ss_lo[l15 * 32 + quad * 8];
        bf16x8 sf1 = *(const bf16x8*)&ss_hi[l15 * 32 + quad * 8];
#pragma unroll
        for (int j = 0; j < 4; ++j) {
            accT[j] = mfma16(va0[j], sf0, accT[j]);
            accT[j] = mfma16(va1[j], sf1, accT[j]);
        }
    }

    if (direct) {
#pragma unroll
        for (int j = 0; j < 4; ++j) {
            short4v pk;
#pragma unroll
            for (int r = 0; r < 4; ++r) pk[r] = f2bf(accT[j][r]);
            *(short4v*)&outb[(size_t)tlane * DD + h * DH + j * 16 + quad * 4] = pk;
        }
    } else {
        float* pb = part + (((size_t)(h * 32 + tt) * 4 + sc) * 4096);
#pragma unroll
        for (int j = 0; j < 4; ++j)
            *(f32x4*)&pb[(myt + l15) * 64 + j * 16 + quad * 4] = accT[j];
    }
}

// ---------------------------------------------------------------------------
// 4. reduce multi-chunk partials -> outb bf16
// ---------------------------------------------------------------------------
__global__ __launch_bounds__(256) void attn_reduce(const float* __restrict__ part,
                                                   const int* __restrict__ aux,
                                                   short* __restrict__ outb) {
    int h = blockIdx.x, tt = blockIdx.y;
    int sc_lo = aux[tt] >> 3, sc_hi = tt >> 3;
    if (sc_lo == sc_hi) return;  // direct path already wrote outb
    int t0 = tt * 64;
    int tid = threadIdx.x;
    int tl16 = tid >> 4, e4 = (tid & 15) * 4;
    const float* pb = part + ((size_t)(h * 32 + tt) * 4) * 4096;
#pragma unroll
    for (int p = 0; p < 4; ++p) {
        int tl = p * 16 + tl16;
        float4 acc = make_float4(0.f, 0.f, 0.f, 0.f);
        for (int sc = sc_lo; sc <= sc_hi; ++sc) {
            float4 v = *(const float4*)&pb[sc * 4096 + tl * 64 + e4];
            acc.x += v.x; acc.y += v.y; acc.z += v.z; acc.w += v.w;
        }
        short4v pk;
        pk[0] = f2bf(acc.x); pk[1] = f2bf(acc.y); pk[2] = f2bf(acc.z); pk[3] = f2bf(acc.w);
        *(short4v*)&outb[(size_t)(t0 + tl) * DD + h * DH + e4] = pk;
    }
}

// ---------------------------------------------------------------------------
// 5. out-proj GEMM
// ---------------------------------------------------------------------------
__global__ __launch_bounds__(256) void gemm_out(const short* __restrict__ A,
                                                const short* __restrict__ BT,
                                                const float* __restrict__ bias,
                                                float* __restrict__ Cout,
                                                int M, int N, int K) {
    __shared__ short As[128 * 32];
    __shared__ short Bs[128 * 32];
    int tid = threadIdx.x;
    int wave = tid >> 6, lane = tid & 63;
    int quad = lane >> 4, l15 = lane & 15;
    int m0 = blockIdx.x * 128, n0 = blockIdx.y * 128;
    int wr = (wave >> 1) * 64, wc = (wave & 1) * 64;

    int srow = wave * 16 + (lane >> 2);
    int scol = (lane & 3) * 8;
    const short* Ag = A + (size_t)(m0 + srow) * K + scol;
    const short* Bg = BT + (size_t)(n0 + srow) * K + scol;
    short* As0 = &As[(wave * 16) * 32];
    short* As1 = &As[(64 + wave * 16) * 32];
    short* Bs0 = &Bs[(wave * 16) * 32];
    short* Bs1 = &Bs[(64 + wave * 16) * 32];

    f32x4 acc[4][4] = {};
    for (int k0 = 0; k0 < K; k0 += 32) {
        __syncthreads();
        gload16(Ag + k0, As0);
        gload16(Ag + (size_t)64 * K + k0, As1);
        gload16(Bg + k0, Bs0);
        gload16(Bg + (size_t)64 * K + k0, Bs1);
        __syncthreads();
        bf16x8 af[4], bfr[4];
#pragma unroll
        for (int i = 0; i < 4; ++i) {
            af[i]  = *(const bf16x8*)&As[(wr + i * 16 + l15) * 32 + quad * 8];
            bfr[i] = *(const bf16x8*)&Bs[(wc + i * 16 + l15) * 32 + quad * 8];
        }
#pragma unroll
        for (int i = 0; i < 4; ++i)
#pragma unroll
            for (int j = 0; j < 4; ++j)
                acc[i][j] = mfma16(af[i], bfr[j], acc[i][j]);
    }
#pragma unroll
    for (int i = 0; i < 4; ++i)
#pragma unroll
        for (int j = 0; j < 4; ++j)
#pragma unroll
            for (int r = 0; r < 4; ++r) {
                int row = m0 + wr + i * 16 + quad * 4 + r;
                int col = n0 + wc + j * 16 + l15;
                Cout[(size_t)row * N + col] = acc[i][j][r] + bias[col];
            }
}

// ---------------------------------------------------------------------------
// Host launcher
// ---------------------------------------------------------------------------
extern "C" void kernel_launch(void* const* d_in, const int* in_sizes, int n_in,
                              void* d_out, int out_size, void* d_ws, size_t ws_size,
                              hipStream_t stream) {
    const float* state = (const float*)d_in[0];
    const float* x     = (const float*)d_in[1];
    const int*   done  = (const int*)d_in[2];
    const float* w_qkv = (const float*)d_in[3];
    const float* b_qkv = (const float*)d_in[4];
    const float* w_out = (const float*)d_in[5];
    const float* b_out = (const float*)d_in[6];

    char* ws = (char*)d_ws;
    int*   seg    = (int*)ws;                         // 8 KB
    int*   totalp = (int*)(ws + 8192);
    int*   aux    = (int*)(ws + 8256);                // 33 ints
    short* wqT    = (short*)(ws + 8448);              // 6 MB   [3072][1024]
    short* woT    = (short*)(ws + 6299904);           // 2 MB   [1024][1024]
    short* stT    = (short*)(ws + 8397056);           // 128 KB [h][e][d]
    short* qk     = (short*)(ws + 8528128);           // 8 MB   [T][2048] (Q|K)
    short* vt     = (short*)(ws + 16916736);          // 4 MB   [h][e][T]
    short* xbf_outb = (short*)(ws + 21111040);        // 4 MB   x_bf then outb
    float* part   = (float*)(ws + 25305344);          // 32 MB  [h][tt][sc][64][64]
    // total 58,859,776 B

    float* new_state_out = (float*)d_out;
    float* x_out         = (float*)d_out + HH * DH * DH;

    prep_kernel<<<2129, 256, 0, stream>>>(x, w_qkv, w_out, state, done,
                                          xbf_outb, wqT, woT, stT,
                                          new_state_out, seg, totalp, aux);

    gemm_qkv<<<dim3(TT / 128, QKV_N / 128), 256, 0, stream>>>(
        xbf_outb, wqT, b_qkv, qk, vt);

    attn_mfma<<<dim3(HH, TT / 64, 5), 256, 0, stream>>>(
        qk, vt, stT, seg, totalp, aux, xbf_outb, part, new_state_out);

    attn_reduce<<<dim3(HH, TT / 64), 256, 0, stream>>>(part, aux, xbf_outb);

    gemm_out<<<dim3(TT / 128, DD / 128), 256, 0, stream>>>(
        xbf_outb, woT, b_out, x_out, TT, DD, DD);
}

// Round 7
// 161.859 us; speedup vs baseline: 1.2270x; 1.1140x over previous
//
#include <hip/hip_runtime.h>

#define TT 2048
#define DD 1024
#define HH 16
#define DH 64
#define QKV_N 3072
#define QKW 2048  // qk buffer width (Q cols 0..1023, K cols 1024..2047)

typedef __attribute__((ext_vector_type(8))) short bf16x8;
typedef __attribute__((ext_vector_type(4))) short short4v;
typedef __attribute__((ext_vector_type(4))) float f32x4;

__device__ inline short f2bf(float f) {
    union { float f; unsigned u; } v; v.f = f;
    unsigned r = v.u + 0x7fff + ((v.u >> 16) & 1);  // RNE
    return (short)(r >> 16);
}

__device__ inline f32x4 mfma16(bf16x8 a, bf16x8 b, f32x4 c) {
    return __builtin_amdgcn_mfma_f32_16x16x32_bf16(a, b, c, 0, 0, 0);
}

__device__ __forceinline__ void gload16(const void* g, void* l) {
    __builtin_amdgcn_global_load_lds(
        (const __attribute__((address_space(1))) unsigned int*)g,
        (__attribute__((address_space(3))) unsigned int*)l, 16, 0, 0);
}

// ---------------------------------------------------------------------------
// 1. prep: x cast, weight/state transposes, new_state init, scan
// ---------------------------------------------------------------------------
__device__ void transpose_tile(const float* __restrict__ in, short* __restrict__ out,
                               int R, int C, int r0, int c0, float (*tile)[65]) {
    int tid = threadIdx.x;
#pragma unroll
    for (int p = 0; p < 4; ++p) {
        int ch = tid + p * 256;
        int r = ch >> 4, c4 = (ch & 15) * 4;
        float4 v = *(const float4*)&in[(size_t)(r0 + r) * C + c0 + c4];
        tile[r][c4] = v.x; tile[r][c4 + 1] = v.y; tile[r][c4 + 2] = v.z; tile[r][c4 + 3] = v.w;
    }
    __syncthreads();
#pragma unroll
    for (int p = 0; p < 2; ++p) {
        int ch = tid + p * 256;
        int c = ch >> 3, r8 = (ch & 7) * 8;
        short tmp[8];
#pragma unroll
        for (int i = 0; i < 8; ++i) tmp[i] = f2bf(tile[r8 + i][c]);
        *(float4*)&out[(size_t)(c0 + c) * R + r0 + r8] = *(float4*)tmp;
    }
}

__global__ __launch_bounds__(256) void prep_kernel(const float* __restrict__ x,
                                                   const float* __restrict__ w_qkv,
                                                   const float* __restrict__ w_out,
                                                   const float* __restrict__ state,
                                                   const int* __restrict__ done,
                                                   short* __restrict__ x_bf,
                                                   short* __restrict__ wqT,
                                                   short* __restrict__ woT,
                                                   short* __restrict__ stT,
                                                   float* __restrict__ stout,
                                                   int* __restrict__ seg,
                                                   int* __restrict__ totalp,
                                                   int* __restrict__ aux) {
    __shared__ float tile[64][65];
    __shared__ int scanbuf[2048 + 512 + 1];
    int b = blockIdx.x;
    int tid = threadIdx.x;
    if (b < 1024) {
        int i = (b * 256 + tid) * 8;
        float4 a = *(const float4*)&x[i];
        float4 c = *(const float4*)&x[i + 4];
        short tmp[8] = {f2bf(a.x), f2bf(a.y), f2bf(a.z), f2bf(a.w),
                        f2bf(c.x), f2bf(c.y), f2bf(c.z), f2bf(c.w)};
        *(float4*)&x_bf[i] = *(float4*)tmp;
    } else if (b < 1792) {
        int bb = b - 1024;
        transpose_tile(w_qkv, wqT, DD, QKV_N, (bb & 15) * 64, (bb >> 4) * 64, tile);
    } else if (b < 2048) {
        int bb = b - 1792;
        transpose_tile(w_out, woT, DD, DD, (bb & 15) * 64, (bb >> 4) * 64, tile);
    } else if (b < 2064) {
        int h = b - 2048;
        transpose_tile(state + (size_t)h * 4096, stT + (size_t)h * 4096, DH, DH, 0, 0, tile);
    } else if (b < 2128) {
        __shared__ int anyf;
        if (tid == 0) anyf = 0;
        __syncthreads();
        int acc = 0;
#pragma unroll
        for (int i = 0; i < 8; ++i) acc |= done[tid * 8 + i];
        if (acc) anyf = 1;
        __syncthreads();
        int f = ((b - 2064) * 256 + tid) * 4;
        float4 v = anyf ? make_float4(0.f, 0.f, 0.f, 0.f) : *(const float4*)&state[f];
        *(float4*)&stout[f] = v;
    } else {
        int* segl = scanbuf;
        int* part = scanbuf + 2048;
        int* excl = scanbuf + 2304;
        int base = tid * 8;
        int local[8];
        int run = 0;
#pragma unroll
        for (int i = 0; i < 8; ++i) { run += (done[base + i] != 0) ? 1 : 0; local[i] = run; }
        part[tid] = run;
        __syncthreads();
        if (tid < 64) {
            int p4[4];
#pragma unroll
            for (int i = 0; i < 4; ++i) p4[i] = part[tid * 4 + i];
            int s = p4[0] + p4[1] + p4[2] + p4[3];
            int v = s;
#pragma unroll
            for (int off = 1; off < 64; off <<= 1) {
                int u = __shfl_up(v, off);
                if (tid >= off) v += u;
            }
            int ex = v - s;
#pragma unroll
            for (int i = 0; i < 4; ++i) { excl[tid * 4 + i] = ex; ex += p4[i]; }
            if (tid == 63) { totalp[0] = v; scanbuf[2560] = v; }
        }
        __syncthreads();
        int off = excl[tid];
#pragma unroll
        for (int i = 0; i < 8; ++i) {
            int sv = off + local[i];
            seg[base + i] = sv;
            segl[base + i] = sv;
        }
        __syncthreads();
        if (tid < 33) {
            int target = (tid < 32) ? segl[tid * 64] : scanbuf[2560];
            int lo = 0, hi = 2047;
            while (lo < hi) { int mid = (lo + hi) >> 1; if (segl[mid] >= target) hi = mid; else lo = mid + 1; }
            aux[tid] = lo >> 6;
        }
    }
}

// ---------------------------------------------------------------------------
// 2. QKV GEMM (m97 pattern): cols <2048 -> qk natural; cols >=2048 -> vt[h][e][t]
// ---------------------------------------------------------------------------
__global__ __launch_bounds__(256) void gemm_qkv(const short* __restrict__ A,
                                                const short* __restrict__ BT,
                                                const float* __restrict__ bias,
                                                short* __restrict__ qk,
                                                short* __restrict__ vt) {
    __shared__ __align__(16) short As[128 * 32];
    __shared__ __align__(16) short Bs[128 * 32];
    const int K = DD;
    int tid = threadIdx.x;
    int wave = tid >> 6, lane = tid & 63;
    int quad = lane >> 4, l15 = lane & 15;
    int m0 = blockIdx.x * 128, n0 = blockIdx.y * 128;
    int wr = (wave >> 1) * 64, wc = (wave & 1) * 64;

    int srow = wave * 16 + (lane >> 2);
    int scol = (lane & 3) * 8;
    const short* Ag = A + (size_t)(m0 + srow) * K + scol;
    const short* Bg = BT + (size_t)(n0 + srow) * K + scol;
    short* As0 = &As[(wave * 16) * 32];
    short* As1 = &As[(64 + wave * 16) * 32];
    short* Bs0 = &Bs[(wave * 16) * 32];
    short* Bs1 = &Bs[(64 + wave * 16) * 32];

    f32x4 acc[4][4] = {};
    for (int k0 = 0; k0 < K; k0 += 32) {
        __syncthreads();
        gload16(Ag + k0, As0);
        gload16(Ag + (size_t)64 * K + k0, As1);
        gload16(Bg + k0, Bs0);
        gload16(Bg + (size_t)64 * K + k0, Bs1);
        __syncthreads();
        bf16x8 af[4], bfr[4];
#pragma unroll
        for (int i = 0; i < 4; ++i) {
            af[i]  = *(const bf16x8*)&As[(wr + i * 16 + l15) * 32 + quad * 8];
            bfr[i] = *(const bf16x8*)&Bs[(wc + i * 16 + l15) * 32 + quad * 8];
        }
#pragma unroll
        for (int i = 0; i < 4; ++i)
#pragma unroll
            for (int j = 0; j < 4; ++j)
                acc[i][j] = mfma16(af[i], bfr[j], acc[i][j]);
    }

    if (n0 < 2048) {
#pragma unroll
        for (int i = 0; i < 4; ++i)
#pragma unroll
            for (int j = 0; j < 4; ++j)
#pragma unroll
                for (int r = 0; r < 4; ++r) {
                    int row = m0 + wr + i * 16 + quad * 4 + r;
                    int col = n0 + wc + j * 16 + l15;
                    qk[(size_t)row * QKW + col] = f2bf(acc[i][j][r] + bias[col]);
                }
    } else {
#pragma unroll
        for (int j = 0; j < 4; ++j) {
            int col = n0 + wc + j * 16 + l15;
            float bv = bias[col];
            int eg = col - 2048;
            int hh = eg >> 6, e = eg & 63;
#pragma unroll
            for (int i = 0; i < 4; ++i) {
                int tb = m0 + wr + i * 16 + quad * 4;
                short4v pk;
#pragma unroll
                for (int r = 0; r < 4; ++r) pk[r] = f2bf(acc[i][j][r] + bv);
                *(short4v*)&vt[(size_t)hh * (DH * TT) + (size_t)e * TT + tb] = pk;
            }
        }
    }
}

// ---------------------------------------------------------------------------
// 3. attention — m97-style LDS staging. grid (H, 16 t-blocks of 128, z:0..3
//    s-chunks of 8 64-tiles + z=4 state). 4 waves x 32 t-rows. Natural [t][e]
//    output; A=S wave-private round-trip; coalesced gload16 K/V staging.
// ---------------------------------------------------------------------------
__global__ __launch_bounds__(256) void attn_mfma(const short* __restrict__ qk,
                                                 const short* __restrict__ vt,
                                                 const short* __restrict__ stT,
                                                 const int* __restrict__ seg,
                                                 const int* __restrict__ totalp,
                                                 const int* __restrict__ aux,
                                                 short* __restrict__ outb,
                                                 float* __restrict__ part,
                                                 float* __restrict__ nsout) {
    __shared__ __align__(16) short Kh[2][64 * 32];   // [d-half][s][32]
    __shared__ __align__(16) short Vh[2][64 * 32];   // [s-half][e][32]
    __shared__ __align__(16) short Qh[2][128 * 32];  // [d-half][t][32]
    __shared__ __align__(16) short Ss[128 * 72];     // [t][s] masked, stride 72

    int h = blockIdx.x, tb = blockIdx.y, sc = blockIdx.z;
    int t0 = tb * 128;
    int tid = threadIdx.x, wave = tid >> 6, lane = tid & 63;
    int quad = lane >> 4, l15 = lane & 15;
    int myt = wave * 32;
    const short* vbase = vt + (size_t)h * (DH * TT);

    if (sc == 4) {
        // ---- state path: chunks ct = 2tb, 2tb+1; atomicAdd onto nsout
        int total = totalp[0];
        int myd = wave * 16;
#pragma unroll
        for (int cc = 0; cc < 2; ++cc) {
            int ct = tb * 2 + cc;
            if (ct < aux[32]) continue;
            int t0c = ct * 64;
            bool keep = (seg[t0c + lane] == total);
            const short* src = qk + (size_t)(t0c + lane) * QKW + 1024 + h * DH + myd;
            union { float4 f; short s[8]; } u0, u1;
            u0.f = keep ? *(const float4*)src : make_float4(0.f, 0.f, 0.f, 0.f);
            u1.f = keep ? *(const float4*)(src + 8) : make_float4(0.f, 0.f, 0.f, 0.f);
            short* dst = (lane < 32) ? &Kh[0][lane] : &Kh[1][lane - 32];
#pragma unroll
            for (int i = 0; i < 8; ++i) {
                dst[(myd + i) * 32] = u0.s[i];
                dst[(myd + 8 + i) * 32] = u1.s[i];
            }
            bf16x8 a0 = *(const bf16x8*)&Kh[0][(myd + l15) * 32 + quad * 8];
            bf16x8 a1 = *(const bf16x8*)&Kh[1][(myd + l15) * 32 + quad * 8];
            f32x4 acc2[4] = {};
#pragma unroll
            for (int j = 0; j < 4; ++j) {
                const short* vrow = vbase + (size_t)(j * 16 + l15) * TT + t0c + quad * 8;
                bf16x8 b0 = *(const bf16x8*)vrow;
                bf16x8 b1 = *(const bf16x8*)(vrow + 32);
                acc2[j] = mfma16(a0, b0, acc2[j]);
                acc2[j] = mfma16(a1, b1, acc2[j]);
            }
            float* oh = nsout + (size_t)h * 4096;
#pragma unroll
            for (int j = 0; j < 4; ++j)
#pragma unroll
                for (int r = 0; r < 4; ++r)
                    atomicAdd(&oh[(myd + quad * 4 + r) * DH + j * 16 + l15], acc2[j][r]);
        }
        return;
    }

    int st0 = aux[2 * tb];                 // earliest 64-tile needed (first row)
    int sc_lo = st0 >> 3, sc_hi = (2 * tb + 1) >> 3;
    if (sc < sc_lo || sc > sc_hi) return;  // block-uniform
    bool direct = (sc_lo == sc_hi);
    int st_lo = (st0 > sc * 8) ? st0 : sc * 8;
    int st_hi = (2 * tb + 1 < sc * 8 + 7) ? 2 * tb + 1 : sc * 8 + 7;

    // ---- stage Q block (128 x 64) into Qh halves, coalesced
    {
        int srow = (lane >> 2);
        int chunk = (lane & 3);
#pragma unroll
        for (int h2 = 0; h2 < 2; ++h2)
#pragma unroll
            for (int q = 0; q < 2; ++q) {
                int row = myt + q * 16 + srow;
                gload16(qk + (size_t)(t0 + row) * QKW + h * DH + h2 * 32 + chunk * 8,
                        &Qh[h2][(myt + q * 16) * 32]);
            }
    }
    __syncthreads();

    bf16x8 af[2][2];
#pragma unroll
    for (int i = 0; i < 2; ++i)
#pragma unroll
        for (int h2 = 0; h2 < 2; ++h2)
            af[i][h2] = *(const bf16x8*)&Qh[h2][(myt + i * 16 + l15) * 32 + quad * 8];

    int tg[2][4], segt[2][4];
#pragma unroll
    for (int i = 0; i < 2; ++i)
#pragma unroll
        for (int r = 0; r < 4; ++r) {
            tg[i][r] = t0 + myt + i * 16 + quad * 4 + r;
            segt[i][r] = seg[tg[i][r]];
        }

    f32x4 acc[2][4] = {};
    if (sc == sc_lo && seg[t0] == 0) {
        const short* sb = stT + (size_t)h * 4096;  // [e][d]
#pragma unroll
        for (int j = 0; j < 4; ++j)
#pragma unroll
            for (int h2 = 0; h2 < 2; ++h2) {
                bf16x8 b = *(const bf16x8*)(sb + (j * 16 + l15) * 64 + h2 * 32 + quad * 8);
#pragma unroll
                for (int i = 0; i < 2; ++i)
                    acc[i][j] = mfma16(af[i][h2], b, acc[i][j]);
            }
#pragma unroll
        for (int i = 0; i < 2; ++i)
#pragma unroll
            for (int r = 0; r < 4; ++r)
                if (segt[i][r] != 0)
#pragma unroll
                    for (int j = 0; j < 4; ++j) acc[i][j][r] = 0.f;
    }

    int srow = wave * 16 + (lane >> 2);
    int chunk = (lane & 3);
    const short* kg = qk + 1024 + h * DH;

    for (int st = st_lo; st <= st_hi; ++st) {
        int s0 = st * 64;
        __syncthreads();  // prior iteration's LDS reads done
        // stage K tile [s][d] halves + V^T tile [e][s] halves, coalesced
        gload16(kg + (size_t)(s0 + srow) * QKW + chunk * 8,        &Kh[0][(wave * 16) * 32]);
        gload16(kg + (size_t)(s0 + srow) * QKW + 32 + chunk * 8,   &Kh[1][(wave * 16) * 32]);
        gload16(vbase + (size_t)srow * TT + s0 + chunk * 8,        &Vh[0][(wave * 16) * 32]);
        gload16(vbase + (size_t)srow * TT + s0 + 32 + chunk * 8,   &Vh[1][(wave * 16) * 32]);
        __syncthreads();  // staged data visible

        int segs[4], sg[4];
#pragma unroll
        for (int j = 0; j < 4; ++j) { sg[j] = s0 + j * 16 + l15; segs[j] = seg[sg[j]]; }

        // S = Q K^T  (D[t][s])
        f32x4 sacc[2][4] = {};
#pragma unroll
        for (int j = 0; j < 4; ++j)
#pragma unroll
            for (int h2 = 0; h2 < 2; ++h2) {
                bf16x8 kb = *(const bf16x8*)&Kh[h2][(j * 16 + l15) * 32 + quad * 8];
#pragma unroll
                for (int i = 0; i < 2; ++i)
                    sacc[i][j] = mfma16(af[i][h2], kb, sacc[i][j]);
            }
        // mask + wave-private Ss write (rows myt..myt+31)
#pragma unroll
        for (int i = 0; i < 2; ++i)
#pragma unroll
            for (int j = 0; j < 4; ++j)
#pragma unroll
                for (int r = 0; r < 4; ++r) {
                    bool ok = (segs[j] == segt[i][r]) && (sg[j] <= tg[i][r]);
                    Ss[(myt + i * 16 + quad * 4 + r) * 72 + j * 16 + l15] =
                        ok ? f2bf(sacc[i][j][r]) : (short)0;
                }
        // out += S @ V  (A = Ss rows, B = Vh)
        bf16x8 sf[2][2];
#pragma unroll
        for (int i = 0; i < 2; ++i)
#pragma unroll
            for (int h2 = 0; h2 < 2; ++h2)
                sf[i][h2] = *(const bf16x8*)&Ss[(myt + i * 16 + l15) * 72 + h2 * 32 + quad * 8];
#pragma unroll
        for (int j = 0; j < 4; ++j)
#pragma unroll
            for (int h2 = 0; h2 < 2; ++h2) {
                bf16x8 vb = *(const bf16x8*)&Vh[h2][(j * 16 + l15) * 32 + quad * 8];
#pragma unroll
                for (int i = 0; i < 2; ++i)
                    acc[i][j] = mfma16(sf[i][h2], vb, acc[i][j]);
            }
    }

    if (direct) {
#pragma unroll
        for (int i = 0; i < 2; ++i)
#pragma unroll
            for (int j = 0; j < 4; ++j)
#pragma unroll
                for (int r = 0; r < 4; ++r)
                    outb[(size_t)tg[i][r] * DD + h * DH + j * 16 + l15] = f2bf(acc[i][j][r]);
    } else {
        float* pb = part + ((size_t)((h * 16 + tb) * 4 + sc)) * 8192;  // [128][64]
#pragma unroll
        for (int i = 0; i < 2; ++i)
#pragma unroll
            for (int j = 0; j < 4; ++j)
#pragma unroll
                for (int r = 0; r < 4; ++r)
                    pb[(myt + i * 16 + quad * 4 + r) * 64 + j * 16 + l15] = acc[i][j][r];
    }
}

// ---------------------------------------------------------------------------
// 4. reduce multi-chunk partials -> outb bf16
// ---------------------------------------------------------------------------
__global__ __launch_bounds__(256) void attn_reduce(const float* __restrict__ part,
                                                   const int* __restrict__ aux,
                                                   short* __restrict__ outb) {
    int h = blockIdx.x, tb = blockIdx.y;
    int sc_lo = aux[2 * tb] >> 3, sc_hi = (2 * tb + 1) >> 3;
    if (sc_lo == sc_hi) return;
    int t0 = tb * 128;
    int tid = threadIdx.x;
    const float* pb = part + ((size_t)(h * 16 + tb) * 4) * 8192;
#pragma unroll
    for (int p = 0; p < 8; ++p) {
        int idx = p * 256 + tid;        // 0..2047 over [128][16 f4-chunks]
        int row = idx >> 4, c4 = (idx & 15) * 4;
        float4 acc = make_float4(0.f, 0.f, 0.f, 0.f);
        for (int sc = sc_lo; sc <= sc_hi; ++sc) {
            float4 v = *(const float4*)&pb[(size_t)sc * 8192 + row * 64 + c4];
            acc.x += v.x; acc.y += v.y; acc.z += v.z; acc.w += v.w;
        }
        short4v pk;
        pk[0] = f2bf(acc.x); pk[1] = f2bf(acc.y); pk[2] = f2bf(acc.z); pk[3] = f2bf(acc.w);
        *(short4v*)&outb[(size_t)(t0 + row) * DD + h * DH + c4] = pk;
    }
}

// ---------------------------------------------------------------------------
// 5. out-proj GEMM
// ---------------------------------------------------------------------------
__global__ __launch_bounds__(256) void gemm_out(const short* __restrict__ A,
                                                const short* __restrict__ BT,
                                                const float* __restrict__ bias,
                                                float* __restrict__ Cout,
                                                int M, int N, int K) {
    __shared__ __align__(16) short As[128 * 32];
    __shared__ __align__(16) short Bs[128 * 32];
    int tid = threadIdx.x;
    int wave = tid >> 6, lane = tid & 63;
    int quad = lane >> 4, l15 = lane & 15;
    int m0 = blockIdx.x * 128, n0 = blockIdx.y * 128;
    int wr = (wave >> 1) * 64, wc = (wave & 1) * 64;

    int srow = wave * 16 + (lane >> 2);
    int scol = (lane & 3) * 8;
    const short* Ag = A + (size_t)(m0 + srow) * K + scol;
    const short* Bg = BT + (size_t)(n0 + srow) * K + scol;
    short* As0 = &As[(wave * 16) * 32];
    short* As1 = &As[(64 + wave * 16) * 32];
    short* Bs0 = &Bs[(wave * 16) * 32];
    short* Bs1 = &Bs[(64 + wave * 16) * 32];

    f32x4 acc[4][4] = {};
    for (int k0 = 0; k0 < K; k0 += 32) {
        __syncthreads();
        gload16(Ag + k0, As0);
        gload16(Ag + (size_t)64 * K + k0, As1);
        gload16(Bg + k0, Bs0);
        gload16(Bg + (size_t)64 * K + k0, Bs1);
        __syncthreads();
        bf16x8 af[4], bfr[4];
#pragma unroll
        for (int i = 0; i < 4; ++i) {
            af[i]  = *(const bf16x8*)&As[(wr + i * 16 + l15) * 32 + quad * 8];
            bfr[i] = *(const bf16x8*)&Bs[(wc + i * 16 + l15) * 32 + quad * 8];
        }
#pragma unroll
        for (int i = 0; i < 4; ++i)
#pragma unroll
            for (int j = 0; j < 4; ++j)
                acc[i][j] = mfma16(af[i], bfr[j], acc[i][j]);
    }
#pragma unroll
    for (int i = 0; i < 4; ++i)
#pragma unroll
        for (int j = 0; j < 4; ++j)
#pragma unroll
            for (int r = 0; r < 4; ++r) {
                int row = m0 + wr + i * 16 + quad * 4 + r;
                int col = n0 + wc + j * 16 + l15;
                Cout[(size_t)row * N + col] = acc[i][j][r] + bias[col];
            }
}

// ---------------------------------------------------------------------------
// Host launcher
// ---------------------------------------------------------------------------
extern "C" void kernel_launch(void* const* d_in, const int* in_sizes, int n_in,
                              void* d_out, int out_size, void* d_ws, size_t ws_size,
                              hipStream_t stream) {
    const float* state = (const float*)d_in[0];
    const float* x     = (const float*)d_in[1];
    const int*   done  = (const int*)d_in[2];
    const float* w_qkv = (const float*)d_in[3];
    const float* b_qkv = (const float*)d_in[4];
    const float* w_out = (const float*)d_in[5];
    const float* b_out = (const float*)d_in[6];

    char* ws = (char*)d_ws;
    int*   seg    = (int*)ws;                         // 8 KB
    int*   totalp = (int*)(ws + 8192);
    int*   aux    = (int*)(ws + 8256);                // 33 ints
    short* wqT    = (short*)(ws + 8448);              // 6 MB   [3072][1024]
    short* woT    = (short*)(ws + 6299904);           // 2 MB   [1024][1024]
    short* stT    = (short*)(ws + 8397056);           // 128 KB [h][e][d]
    short* qk     = (short*)(ws + 8528128);           // 8 MB   [T][2048] (Q|K)
    short* vt     = (short*)(ws + 16916736);          // 4 MB   [h][e][T]
    short* xbf_outb = (short*)(ws + 21111040);        // 4 MB   x_bf then outb
    float* part   = (float*)(ws + 25305344);          // 16 MB  [h][tb][sc][128][64]

    float* new_state_out = (float*)d_out;
    float* x_out         = (float*)d_out + HH * DH * DH;

    prep_kernel<<<2129, 256, 0, stream>>>(x, w_qkv, w_out, state, done,
                                          xbf_outb, wqT, woT, stT,
                                          new_state_out, seg, totalp, aux);

    gemm_qkv<<<dim3(TT / 128, QKV_N / 128), 256, 0, stream>>>(
        xbf_outb, wqT, b_qkv, qk, vt);

    attn_mfma<<<dim3(HH, TT / 128, 5), 256, 0, stream>>>(
        qk, vt, stT, seg, totalp, aux, xbf_outb, part, new_state_out);

    attn_reduce<<<dim3(HH, TT / 128), 256, 0, stream>>>(part, aux, xbf_outb);

    gemm_out<<<dim3(TT / 128, DD / 128), 256, 0, stream>>>(
        xbf_outb, woT, b_out, x_out, TT, DD, DD);
}